// Round 8
// baseline (78.069 us; speedup 1.0000x reference)
//
#include <hip/hip_runtime.h>

#define EPSF 1e-7f
#define TS2 72   // bf16 row stride: 64 + 8 pad (144 B = 16B-aligned rows)

typedef __bf16 bf16;
typedef __attribute__((ext_vector_type(8))) __bf16 bf16x8;
typedef __attribute__((ext_vector_type(4))) __bf16 bf16x4;
typedef __attribute__((ext_vector_type(4))) float f32x4;
typedef __attribute__((ext_vector_type(2))) float f32x2;

// Sum across the 4 quads (lanes ^16, ^32). 2 ops.
__device__ __forceinline__ float quad_sum(float v) {
  v += __shfl_xor(v, 16, 64);
  v += __shfl_xor(v, 32, 64);
  return v;
}

// One block = one sample n; 4 waves; wave wv owns o-channels [16wv,16wv+16).
// BOTH GEMMs use swapped operand roles (A/B frag layouts are identical on
// gfx950):
//   GEMM1: dot[i][o] = mfma(A=X(xrf regs), B=a-row)  -> lane owns o=olane
//   GEMM2: G^T[dd][o]= mfma(A=Xt-rows,     B=c-row)  -> lane owns o=olane
// it0 UNIFIED into the loop (B=x0f regs) AND DEDUPED: at it0 the D-tile's
// columns are identical (B cols all x0), so acc[t][r] is bit-exactly
// ln15-independent -> factor() is computed ONCE per i per wave:
//   lane l handles i(l)=16*(l&3)+4*quad+((l>>2)&3) = its own acc[l&3][(l>>2)&3]
//   (15-cndmask static select tree), one scalar factor pipeline, then 16
//   __shfl redistributes (src = (lane&48)+4r+t, same quad) feed the c-row
//   build. Same rounding points as the packed path -> bit-identical output.
// sd = <a,G> after GEMM2 (G=sum c*x => sum c*dot = <a,G>); ||grad||^2 =
// <G,G> - sd^2; update folded: a' = (cn - sn*sd)*a + sn*G.
// Elementwise (it1/2) factor pipeline pairwise-packed on f32x2 (v_pk_*).
// Xrow/Xt/AC are separate __shared__ arrays (provably disjoint -> scheduler
// may move Xt/Xrow reads across AC writes).
// Barrier schedule: [stage Xrow] sync [hoists + Xt build + it0 front]
// sync-once [GEMM2 it0; iters 1,2 barrier-free] [4x float4 direct stores].
__global__ __launch_bounds__(256, 4) void mfd_fc_mfma(
    const float* __restrict__ x, const float* __restrict__ wraw,
    float* __restrict__ out) {
  __shared__ __align__(16) bf16 Xrow[64 * TS2];  // [i][dd]
  __shared__ __align__(16) bf16 Xt[64 * TS2];    // [dd][i]
  __shared__ __align__(16) bf16 AC[64 * TS2];    // [o][dd] a-rows / [o][i] c-rows

  const int n = blockIdx.x;
  const int tid = threadIdx.x;
  const int wv = tid >> 6;
  const int lane = tid & 63;
  const int ln15 = lane & 15;
  const int quad = lane >> 4;
  const int q4 = 4 * quad;
  const int olane = 16 * wv + ln15;    // this lane's output channel
  const float* xn = x + (size_t)n * 4096;

  const f32x2 ONE2 = {1.0f, 1.0f};
  const f32x2 PC3 = {-0.0187292994f, -0.0187292994f};
  const f32x2 PC2 = {0.0742610070f, 0.0742610070f};
  const f32x2 PC1 = {-0.2121144013f, -0.2121144013f};
  const f32x2 PC0 = {1.5707288f, 1.5707288f};
  const f32x2 PI2 = {3.14159265358979f, 3.14159265358979f};

  // ---- stage X -> Xrow (bf16), coalesced float4 loads ----
#pragma unroll
  for (int t = 0; t < 4; ++t) {
    int idx = tid + t * 256;  // float4 index
    int i = idx >> 4;
    int c4 = (idx & 15) << 2;
    float4 v = reinterpret_cast<const float4*>(xn)[idx];
    bf16x4 b;
    b[0] = (bf16)v.x; b[1] = (bf16)v.y; b[2] = (bf16)v.z; b[3] = (bf16)v.w;
    *reinterpret_cast<bf16x4*>(&Xrow[i * TS2 + c4]) = b;
  }

  // ---- softmax of wraw column o=olane, transposed layout, packed pairs:
  // wfp[t][h] = {w[16t+q4+2h][olane], w[16t+q4+2h+1][olane]} normalized
  f32x2 wfp[4][2];
  {
    f32x2 cs2 = {0.f, 0.f};
#pragma unroll
    for (int t = 0; t < 4; ++t)
#pragma unroll
      for (int h = 0; h < 2; ++h) {
        f32x2 e;
        e.x = __expf(wraw[(16 * t + q4 + 2 * h) * 64 + olane]);
        e.y = __expf(wraw[(16 * t + q4 + 2 * h + 1) * 64 + olane]);
        wfp[t][h] = e;
        cs2 = cs2 + e;                  // pk_add
      }
    float inv = __builtin_amdgcn_rcpf(quad_sum(cs2.x + cs2.y));
    f32x2 inv2 = {inv, inv};
#pragma unroll
    for (int t = 0; t < 4; ++t)
#pragma unroll
      for (int h = 0; h < 2; ++h) wfp[t][h] = wfp[t][h] * inv2;  // pk_mul
  }

  // ---- a := x0, transposed layout: a_reg[t][r] = x0[dd=16t+q4+r] ----
  float a_reg[4][4];
#pragma unroll
  for (int t = 0; t < 4; ++t) {
    float4 v = *reinterpret_cast<const float4*>(&xn[16 * t + q4]);
    a_reg[t][0] = v.x; a_reg[t][1] = v.y; a_reg[t][2] = v.z; a_reg[t][3] = v.w;
  }

  __syncthreads();  // Xrow complete

  // ---- hoist GEMM1 A-fragments (X rows, loop-invariant): 8 x bf16x8 ----
  bf16x8 xrf[4][2];
#pragma unroll
  for (int t = 0; t < 4; ++t)
#pragma unroll
    for (int ks = 0; ks < 2; ++ks)
      xrf[t][ks] = *reinterpret_cast<const bf16x8*>(
          &Xrow[(16 * t + ln15) * TS2 + ks * 32 + quad * 8]);

  // ---- x0 B-fragment (row 0; chunk depends only on ks,quad — exactly the
  // B-frag layout) for the unified it0 GEMM1
  bf16x8 x0f[2];
#pragma unroll
  for (int ks = 0; ks < 2; ++ks)
    x0f[ks] = *reinterpret_cast<const bf16x8*>(&Xrow[ks * 32 + quad * 8]);

  // ---- build Xt from Xrow (u16 column reads = pair-broadcast) ----
  {
    int dd = tid & 63, ih = tid >> 6;  // i-range [16*ih, 16*ih+16)
    bf16 tmp[16];
#pragma unroll
    for (int j = 0; j < 16; ++j) tmp[j] = Xrow[(16 * ih + j) * TS2 + dd];
    *reinterpret_cast<bf16x8*>(&Xt[dd * TS2 + 16 * ih]) =
        *reinterpret_cast<bf16x8*>(&tmp[0]);
    *reinterpret_cast<bf16x8*>(&Xt[dd * TS2 + 16 * ih + 8]) =
        *reinterpret_cast<bf16x8*>(&tmp[8]);
  }
  // NOTE: no barrier yet — it0 front (MFMA on registers) doesn't touch Xt.

  bf16* acrow = &AC[olane * TS2];   // lane's private o-row (a-row / c-row)
  f32x2* a2 = reinterpret_cast<f32x2*>(&a_reg[0][0]);  // static-indexed only

#pragma unroll
  for (int it = 0; it < 3; ++it) {
    // ---- GEMM1 (swapped): dot[i][o]; A=xrf regs, B = x0f (it0) / a-row ----
    f32x4 acc[4] = {f32x4{0,0,0,0}, f32x4{0,0,0,0}, f32x4{0,0,0,0}, f32x4{0,0,0,0}};
#pragma unroll
    for (int ks = 0; ks < 2; ++ks) {
      bf16x8 bfA = (it == 0)
          ? x0f[ks]
          : *reinterpret_cast<const bf16x8*>(&acrow[ks * 32 + quad * 8]);
#pragma unroll
      for (int t = 0; t < 4; ++t)
        acc[t] = __builtin_amdgcn_mfma_f32_16x16x32_bf16(xrf[t][ks], bfA, acc[t], 0, 0, 0);
    }

    if (it == 0) {
      // ---- it0 dedup: acc[t][r] is ln15-independent (all B cols = x0).
      // Lane handles i(l)=16T+4*quad+R, T=lane&3, R=(lane>>2)&3 — which is
      // its OWN acc[T][R]. Static cndmask tree (no runtime reg indexing).
      bool bT0 = (lane & 1) != 0;
      bool bT1 = (lane & 2) != 0;
      bool bR0 = (lane & 4) != 0;
      bool bR1 = (lane & 8) != 0;
      f32x4 cT0 = bT0 ? acc[1] : acc[0];
      f32x4 cT1 = bT0 ? acc[3] : acc[2];
      f32x4 accT = bT1 ? cT1 : cT0;
      float rr0 = bR0 ? accT[1] : accT[0];
      float rr1 = bR0 ? accT[3] : accT[2];
      float dsel = bR1 ? rr1 : rr0;
      dsel = __builtin_amdgcn_fmed3f(dsel, -1.0f + EPSF, 1.0f - EPSF);
      // scalar fused factor (same rounding points as packed path)
      float ax = fabsf(dsel);
      float q2s = __builtin_amdgcn_rsqf(1.0f + ax);
      float r2s = __builtin_amdgcn_rsqf(1.0f - ax);
      float pa = fmaf(fmaf(fmaf(-0.0187292994f, ax, 0.0742610070f), ax,
                           -0.2121144013f), ax, 1.5707288f);
      float sel = (dsel < 0.0f) ? fmaf(3.14159265358979f, r2s, -pa) : pa;
      float fsel = sel * q2s;
      // redistribute: f0 for slot (t,r) lives in lane (lane&48)+4r+t
      const int srcb = lane & 48;
#pragma unroll
      for (int t = 0; t < 4; ++t) {
        bf16x4 cpk;
#pragma unroll
        for (int h = 0; h < 2; ++h) {
          f32x2 f2;
          f2.x = __shfl(fsel, srcb + 4 * (2 * h) + t, 64);
          f2.y = __shfl(fsel, srcb + 4 * (2 * h + 1) + t, 64);
          f32x2 cf = f2 * wfp[t][h];    // pk_mul
          cpk[2 * h]     = (bf16)cf.x;
          cpk[2 * h + 1] = (bf16)cf.y;
        }
        *reinterpret_cast<bf16x4*>(&acrow[16 * t + q4]) = cpk;  // c-row b64
      }
    } else {
      // ---- elementwise: c = w * factor(dot), packed pairs ----
#pragma unroll
      for (int t = 0; t < 4; ++t) {
        bf16x4 cpk;
#pragma unroll
        for (int h = 0; h < 2; ++h) {
          f32x2 d2;
          d2.x = __builtin_amdgcn_fmed3f(acc[t][2 * h],     -1.0f + EPSF, 1.0f - EPSF);
          d2.y = __builtin_amdgcn_fmed3f(acc[t][2 * h + 1], -1.0f + EPSF, 1.0f - EPSF);
          f32x2 nd = -d2;
          f32x2 ax; ax.x = fmaxf(d2.x, nd.x); ax.y = fmaxf(d2.y, nd.y);  // pk_max
          f32x2 p1 = ONE2 + ax;                 // pk_add
          f32x2 m1 = ONE2 - ax;                 // pk_add (neg)
          f32x2 q2, r2;
          q2.x = __builtin_amdgcn_rsqf(p1.x); q2.y = __builtin_amdgcn_rsqf(p1.y);
          r2.x = __builtin_amdgcn_rsqf(m1.x); r2.y = __builtin_amdgcn_rsqf(m1.y);
          f32x2 pa = PC3 * ax + PC2;            // 3x pk_fma
          pa = pa * ax + PC1;
          pa = pa * ax + PC0;
          f32x2 nb = PI2 * r2 - pa;             // pk_fma (neg)
          f32x2 sel;
          sel.x = (d2.x < 0.f) ? nb.x : pa.x;
          sel.y = (d2.y < 0.f) ? nb.y : pa.y;
          f32x2 cf = (sel * q2) * wfp[t][h];    // 2x pk_mul
          cpk[2 * h]     = (bf16)cf.x;
          cpk[2 * h + 1] = (bf16)cf.y;
        }
        *reinterpret_cast<bf16x4*>(&acrow[16 * t + q4]) = cpk;  // c-row b64
      }
    }

    if (it == 0) __syncthreads();  // Xt complete (hidden behind it0 front)

    // ---- GEMM2 (swapped): G^T[dd][o]; A=Xt rows, B=c-row from AC ----
    f32x4 g[4] = {f32x4{0,0,0,0}, f32x4{0,0,0,0}, f32x4{0,0,0,0}, f32x4{0,0,0,0}};
#pragma unroll
    for (int ks = 0; ks < 2; ++ks) {
      bf16x8 cf = *reinterpret_cast<const bf16x8*>(&acrow[ks * 32 + quad * 8]);
#pragma unroll
      for (int t = 0; t < 4; ++t) {
        bf16x8 xtf = *reinterpret_cast<const bf16x8*>(
            &Xt[(16 * t + ln15) * TS2 + ks * 32 + quad * 8]);
        g[t] = __builtin_amdgcn_mfma_f32_16x16x32_bf16(xtf, cf, g[t], 0, 0, 0);
      }
    }

    // ---- sd = <a,G>, gg = <G,G>  (a is unit: ||G - sd*a||^2 = gg - sd^2)
    f32x2* g2 = reinterpret_cast<f32x2*>(&g[0]);   // static-indexed only
    f32x2 sdp = {0.f, 0.f}, ggp = {0.f, 0.f};
#pragma unroll
    for (int u = 0; u < 8; ++u) {
      sdp = a2[u] * g2[u] + sdp;    // pk_fma
      ggp = g2[u] * g2[u] + ggp;    // pk_fma
    }
    float sdv = quad_sum(sdp.x + sdp.y);
    float gg  = quad_sum(ggp.x + ggp.y);
    float gn2 = fmaxf(gg - sdv * sdv, 0.f);     // guard rounding-negative
    float nrm = __builtin_amdgcn_sqrtf(gn2);
    float rev = nrm * 0.15915494309189535f;     // v_sin/v_cos take revolutions
    float sn_ = __builtin_amdgcn_sinf(rev);
    float cn  = __builtin_amdgcn_cosf(rev);
    float sn = (nrm < EPSF) ? 1.0f : sn_ * __builtin_amdgcn_rcpf(nrm);
    // a' = cn*a + sn*(G - sd*a) = (cn - sn*sd)*a + sn*G
    float coefA = cn - sn * sdv;
    f32x2 cA2 = {coefA, coefA}, sn2 = {sn, sn};
#pragma unroll
    for (int u = 0; u < 8; ++u)
      a2[u] = cA2 * a2[u] + sn2 * g2[u];
    if (it < 2) {
      // a-row writeback [olane][dd] for next GEMM1's B-frag, packed b64
#pragma unroll
      for (int t = 0; t < 4; ++t) {
        bf16x4 apk;
#pragma unroll
        for (int r = 0; r < 4; ++r) apk[r] = (bf16)a_reg[t][r];
        *reinterpret_cast<bf16x4*>(&acrow[16 * t + q4]) = apk;
      }
    }
  }

  // ---- epilogue: 4 float4 direct stores; each quad-row covers a
  // contiguous 64B segment of its o-row. No LDS, no sync.
  float* outn = out + (size_t)n * 4096;
#pragma unroll
  for (int t = 0; t < 4; ++t) {
    float4 v4;
    v4.x = a_reg[t][0]; v4.y = a_reg[t][1];
    v4.z = a_reg[t][2]; v4.w = a_reg[t][3];
    *reinterpret_cast<float4*>(&outn[olane * 64 + 16 * t + q4]) = v4;
  }
}

extern "C" void kernel_launch(void* const* d_in, const int* in_sizes, int n_in,
                              void* d_out, int out_size, void* d_ws, size_t ws_size,
                              hipStream_t stream) {
  const float* x = (const float*)d_in[0];    // (B,L,64,64) fp32, unit rows
  const float* wraw = (const float*)d_in[1]; // (64,64) fp32
  float* out = (float*)d_out;                // (B,L,64,64) fp32
  (void)d_ws; (void)ws_size;

  int N = in_sizes[0] / 4096;  // B*L = 1024
  mfd_fc_mfma<<<N, 256, 0, stream>>>(x, wraw, out);
}

// Round 9
// 77.666 us; speedup vs baseline: 1.0052x; 1.0052x over previous
//
#include <hip/hip_runtime.h>

#define EPSF 1e-7f
#define TS2 72   // bf16 row stride: 64 + 8 pad (144 B = 16B-aligned rows)

typedef __bf16 bf16;
typedef __attribute__((ext_vector_type(8))) __bf16 bf16x8;
typedef __attribute__((ext_vector_type(4))) __bf16 bf16x4;
typedef __attribute__((ext_vector_type(4))) float f32x4;
typedef __attribute__((ext_vector_type(2))) float f32x2;

// Sum across the 4 quads (lanes ^16, ^32). 2 ops.
__device__ __forceinline__ float quad_sum(float v) {
  v += __shfl_xor(v, 16, 64);
  v += __shfl_xor(v, 32, 64);
  return v;
}

// One block = one sample n; 4 waves; wave wv owns o-channels [16wv,16wv+16).
// BOTH GEMMs use swapped operand roles (A/B frag layouts are identical on
// gfx950):
//   GEMM1: dot[i][o] = mfma(A=X(xrf regs), B=a-row)  -> lane owns o=olane
//   GEMM2: G^T[dd][o]= mfma(A=Xt-rows,     B=c-row)  -> lane owns o=olane
// it0 UNIFIED: a0 == x0 and x0f (regs) already has the B-frag layout.
// sd = sum_i c*dot computed as <a,G> AFTER GEMM2 (identity: G=sum c*x
// => sum c*dot = <a,G>); ||grad||^2 = <G,G> - sd^2 (a unit, guarded);
// update folded: a' = (cn - sn*sd)*a + sn*G.
// Xrow/Xt/AC are SEPARATE __shared__ arrays (provably disjoint) so the
// scheduler may move Xt/Xrow reads across AC writes.
// Elementwise factor pipeline pairwise-packed on f32x2 (v_pk_*);
// rsq/fmed3/cmp/cndmask/cvt stay scalar. Same rounding points as scalar.
// NOTE (R8 lesson): deduping the it0 factor work (1 scalar pipeline +
// shfl redistribute) REGRESSED +0.37us — fewer issue slots but a longer
// serial chain gating the it0 barrier. Keep the packed ILP form.
// Barrier schedule: [stage Xrow] sync [hoists + Xt build + it0 front]
// sync-once [GEMM2 it0; iters 1,2 barrier-free] [4x float4 direct stores].
__global__ __launch_bounds__(256, 4) void mfd_fc_mfma(
    const float* __restrict__ x, const float* __restrict__ wraw,
    float* __restrict__ out) {
  __shared__ __align__(16) bf16 Xrow[64 * TS2];  // [i][dd]
  __shared__ __align__(16) bf16 Xt[64 * TS2];    // [dd][i]
  __shared__ __align__(16) bf16 AC[64 * TS2];    // [o][dd] a-rows / [o][i] c-rows

  const int n = blockIdx.x;
  const int tid = threadIdx.x;
  const int wv = tid >> 6;
  const int lane = tid & 63;
  const int ln15 = lane & 15;
  const int quad = lane >> 4;
  const int q4 = 4 * quad;
  const int olane = 16 * wv + ln15;    // this lane's output channel
  const float* xn = x + (size_t)n * 4096;

  const f32x2 ONE2 = {1.0f, 1.0f};
  const f32x2 PC3 = {-0.0187292994f, -0.0187292994f};
  const f32x2 PC2 = {0.0742610070f, 0.0742610070f};
  const f32x2 PC1 = {-0.2121144013f, -0.2121144013f};
  const f32x2 PC0 = {1.5707288f, 1.5707288f};
  const f32x2 PI2 = {3.14159265358979f, 3.14159265358979f};

  // ---- stage X -> Xrow (bf16), coalesced float4 loads ----
#pragma unroll
  for (int t = 0; t < 4; ++t) {
    int idx = tid + t * 256;  // float4 index
    int i = idx >> 4;
    int c4 = (idx & 15) << 2;
    float4 v = reinterpret_cast<const float4*>(xn)[idx];
    bf16x4 b;
    b[0] = (bf16)v.x; b[1] = (bf16)v.y; b[2] = (bf16)v.z; b[3] = (bf16)v.w;
    *reinterpret_cast<bf16x4*>(&Xrow[i * TS2 + c4]) = b;
  }

  // ---- softmax of wraw column o=olane, transposed layout, packed pairs:
  // wfp[t][h] = {w[16t+q4+2h][olane], w[16t+q4+2h+1][olane]} normalized
  f32x2 wfp[4][2];
  {
    f32x2 cs2 = {0.f, 0.f};
#pragma unroll
    for (int t = 0; t < 4; ++t)
#pragma unroll
      for (int h = 0; h < 2; ++h) {
        f32x2 e;
        e.x = __expf(wraw[(16 * t + q4 + 2 * h) * 64 + olane]);
        e.y = __expf(wraw[(16 * t + q4 + 2 * h + 1) * 64 + olane]);
        wfp[t][h] = e;
        cs2 = cs2 + e;                  // pk_add
      }
    float inv = __builtin_amdgcn_rcpf(quad_sum(cs2.x + cs2.y));
    f32x2 inv2 = {inv, inv};
#pragma unroll
    for (int t = 0; t < 4; ++t)
#pragma unroll
      for (int h = 0; h < 2; ++h) wfp[t][h] = wfp[t][h] * inv2;  // pk_mul
  }

  // ---- a := x0, transposed layout: a_reg[t][r] = x0[dd=16t+q4+r] ----
  float a_reg[4][4];
#pragma unroll
  for (int t = 0; t < 4; ++t) {
    float4 v = *reinterpret_cast<const float4*>(&xn[16 * t + q4]);
    a_reg[t][0] = v.x; a_reg[t][1] = v.y; a_reg[t][2] = v.z; a_reg[t][3] = v.w;
  }

  __syncthreads();  // Xrow complete

  // ---- hoist GEMM1 A-fragments (X rows, loop-invariant): 8 x bf16x8 ----
  bf16x8 xrf[4][2];
#pragma unroll
  for (int t = 0; t < 4; ++t)
#pragma unroll
    for (int ks = 0; ks < 2; ++ks)
      xrf[t][ks] = *reinterpret_cast<const bf16x8*>(
          &Xrow[(16 * t + ln15) * TS2 + ks * 32 + quad * 8]);

  // ---- x0 B-fragment (row 0; chunk depends only on ks,quad — exactly the
  // B-frag layout) for the unified it0 GEMM1
  bf16x8 x0f[2];
#pragma unroll
  for (int ks = 0; ks < 2; ++ks)
    x0f[ks] = *reinterpret_cast<const bf16x8*>(&Xrow[ks * 32 + quad * 8]);

  // ---- build Xt from Xrow (u16 column reads = pair-broadcast) ----
  {
    int dd = tid & 63, ih = tid >> 6;  // i-range [16*ih, 16*ih+16)
    bf16 tmp[16];
#pragma unroll
    for (int j = 0; j < 16; ++j) tmp[j] = Xrow[(16 * ih + j) * TS2 + dd];
    *reinterpret_cast<bf16x8*>(&Xt[dd * TS2 + 16 * ih]) =
        *reinterpret_cast<bf16x8*>(&tmp[0]);
    *reinterpret_cast<bf16x8*>(&Xt[dd * TS2 + 16 * ih + 8]) =
        *reinterpret_cast<bf16x8*>(&tmp[8]);
  }
  // NOTE: no barrier yet — it0 front (MFMA on registers) doesn't touch Xt.

  bf16* acrow = &AC[olane * TS2];   // lane's private o-row (a-row / c-row)
  f32x2* a2 = reinterpret_cast<f32x2*>(&a_reg[0][0]);  // static-indexed only

#pragma unroll
  for (int it = 0; it < 3; ++it) {
    // ---- GEMM1 (swapped): dot[i][o]; A=xrf regs, B = x0f (it0) / a-row ----
    f32x4 acc[4] = {f32x4{0,0,0,0}, f32x4{0,0,0,0}, f32x4{0,0,0,0}, f32x4{0,0,0,0}};
#pragma unroll
    for (int ks = 0; ks < 2; ++ks) {
      bf16x8 bfA = (it == 0)
          ? x0f[ks]
          : *reinterpret_cast<const bf16x8*>(&acrow[ks * 32 + quad * 8]);
#pragma unroll
      for (int t = 0; t < 4; ++t)
        acc[t] = __builtin_amdgcn_mfma_f32_16x16x32_bf16(xrf[t][ks], bfA, acc[t], 0, 0, 0);
    }

    // ---- elementwise: c = w * factor(dot), packed pairs (no sd here) ----
#pragma unroll
    for (int t = 0; t < 4; ++t) {
      bf16x4 cpk;
#pragma unroll
      for (int h = 0; h < 2; ++h) {
        f32x2 d2;
        d2.x = __builtin_amdgcn_fmed3f(acc[t][2 * h],     -1.0f + EPSF, 1.0f - EPSF);
        d2.y = __builtin_amdgcn_fmed3f(acc[t][2 * h + 1], -1.0f + EPSF, 1.0f - EPSF);
        f32x2 nd = -d2;
        f32x2 ax; ax.x = fmaxf(d2.x, nd.x); ax.y = fmaxf(d2.y, nd.y);  // pk_max
        f32x2 p1 = ONE2 + ax;                 // pk_add
        f32x2 m1 = ONE2 - ax;                 // pk_add (neg)
        f32x2 q2, r2;
        q2.x = __builtin_amdgcn_rsqf(p1.x); q2.y = __builtin_amdgcn_rsqf(p1.y);
        r2.x = __builtin_amdgcn_rsqf(m1.x); r2.y = __builtin_amdgcn_rsqf(m1.y);
        f32x2 pa = PC3 * ax + PC2;            // 3x pk_fma
        pa = pa * ax + PC1;
        pa = pa * ax + PC0;
        f32x2 nb = PI2 * r2 - pa;             // pk_fma (neg)
        f32x2 sel;
        sel.x = (d2.x < 0.f) ? nb.x : pa.x;
        sel.y = (d2.y < 0.f) ? nb.y : pa.y;
        f32x2 cf = (sel * q2) * wfp[t][h];    // 2x pk_mul
        cpk[2 * h]     = (bf16)cf.x;
        cpk[2 * h + 1] = (bf16)cf.y;
      }
      *reinterpret_cast<bf16x4*>(&acrow[16 * t + q4]) = cpk;  // c-row b64
    }

    if (it == 0) __syncthreads();  // Xt complete (hidden behind it0 front)

    // ---- GEMM2 (swapped): G^T[dd][o]; A=Xt rows, B=c-row from AC ----
    f32x4 g[4] = {f32x4{0,0,0,0}, f32x4{0,0,0,0}, f32x4{0,0,0,0}, f32x4{0,0,0,0}};
#pragma unroll
    for (int ks = 0; ks < 2; ++ks) {
      bf16x8 cf = *reinterpret_cast<const bf16x8*>(&acrow[ks * 32 + quad * 8]);
#pragma unroll
      for (int t = 0; t < 4; ++t) {
        bf16x8 xtf = *reinterpret_cast<const bf16x8*>(
            &Xt[(16 * t + ln15) * TS2 + ks * 32 + quad * 8]);
        g[t] = __builtin_amdgcn_mfma_f32_16x16x32_bf16(xtf, cf, g[t], 0, 0, 0);
      }
    }

    // ---- sd = <a,G>, gg = <G,G>  (a is unit: ||G - sd*a||^2 = gg - sd^2)
    f32x2* g2 = reinterpret_cast<f32x2*>(&g[0]);   // static-indexed only
    f32x2 sdp = {0.f, 0.f}, ggp = {0.f, 0.f};
#pragma unroll
    for (int u = 0; u < 8; ++u) {
      sdp = a2[u] * g2[u] + sdp;    // pk_fma
      ggp = g2[u] * g2[u] + ggp;    // pk_fma
    }
    float sdv = quad_sum(sdp.x + sdp.y);
    float gg  = quad_sum(ggp.x + ggp.y);
    float gn2 = fmaxf(gg - sdv * sdv, 0.f);     // guard rounding-negative
    float nrm = __builtin_amdgcn_sqrtf(gn2);
    float rev = nrm * 0.15915494309189535f;     // v_sin/v_cos take revolutions
    float sn_ = __builtin_amdgcn_sinf(rev);
    float cn  = __builtin_amdgcn_cosf(rev);
    float sn = (nrm < EPSF) ? 1.0f : sn_ * __builtin_amdgcn_rcpf(nrm);
    // a' = cn*a + sn*(G - sd*a) = (cn - sn*sd)*a + sn*G
    float coefA = cn - sn * sdv;
    f32x2 cA2 = {coefA, coefA}, sn2 = {sn, sn};
#pragma unroll
    for (int u = 0; u < 8; ++u)
      a2[u] = cA2 * a2[u] + sn2 * g2[u];
    if (it < 2) {
      // a-row writeback [olane][dd] for next GEMM1's B-frag, packed b64
#pragma unroll
      for (int t = 0; t < 4; ++t) {
        bf16x4 apk;
#pragma unroll
        for (int r = 0; r < 4; ++r) apk[r] = (bf16)a_reg[t][r];
        *reinterpret_cast<bf16x4*>(&acrow[16 * t + q4]) = apk;
      }
    }
  }

  // ---- epilogue: 4 float4 direct stores; each quad-row covers a
  // contiguous 64B segment of its o-row. No LDS, no sync.
  float* outn = out + (size_t)n * 4096;
#pragma unroll
  for (int t = 0; t < 4; ++t) {
    float4 v4;
    v4.x = a_reg[t][0]; v4.y = a_reg[t][1];
    v4.z = a_reg[t][2]; v4.w = a_reg[t][3];
    *reinterpret_cast<float4*>(&outn[olane * 64 + 16 * t + q4]) = v4;
  }
}

extern "C" void kernel_launch(void* const* d_in, const int* in_sizes, int n_in,
                              void* d_out, int out_size, void* d_ws, size_t ws_size,
                              hipStream_t stream) {
  const float* x = (const float*)d_in[0];    // (B,L,64,64) fp32, unit rows
  const float* wraw = (const float*)d_in[1]; // (64,64) fp32
  float* out = (float*)d_out;                // (B,L,64,64) fp32
  (void)d_ws; (void)ws_size;

  int N = in_sizes[0] / 4096;  // B*L = 1024
  mfd_fc_mfma<<<N, 256, 0, stream>>>(x, wraw, out);
}